// Round 18
// baseline (550.400 us; speedup 1.0000x reference)
//
#include <hip/hip_runtime.h>

#define BATCH 16
#define NQ 2048
#define NK 2048

typedef short s16x8 __attribute__((ext_vector_type(8)));
typedef __bf16 bf16x8 __attribute__((ext_vector_type(8)));
typedef float f32x16 __attribute__((ext_vector_type(16)));
typedef float f32x4 __attribute__((ext_vector_type(4)));
typedef int i32x4 __attribute__((ext_vector_type(4)));
typedef unsigned u32x2 __attribute__((ext_vector_type(2)));

static __device__ __forceinline__ unsigned short f2bf(float f) {
  unsigned u = __builtin_bit_cast(unsigned, f);
  u += 0x7FFFu + ((u >> 16) & 1u);   // round-to-nearest-even
  return (unsigned short)(u >> 16);
}

static __device__ __forceinline__ f32x16 mfma32(s16x8 a, s16x8 b, f32x16 c) {
  return __builtin_amdgcn_mfma_f32_32x32x16_bf16(
      __builtin_bit_cast(bf16x8, a), __builtin_bit_cast(bf16x8, b), c, 0, 0, 0);
}

static __device__ __forceinline__ f32x4 mfma16(s16x8 a, s16x8 b, f32x4 c) {
  return __builtin_amdgcn_mfma_f32_16x16x32_bf16(
      __builtin_bit_cast(bf16x8, a), __builtin_bit_cast(bf16x8, b), c, 0, 0, 0);
}

// p = exp(10*tanh(s) - 10) = exp2(-28.8539.../(e^(2s)+1)), e^(2s)=exp2(2.88539*s)
static __device__ __forceinline__ float score_p(float s) {
  float u = __builtin_amdgcn_exp2f(s * 2.885390081777927f);
  return __builtin_amdgcn_exp2f(-28.853900817779268f * __builtin_amdgcn_rcpf(u + 1.0f));
}

// WT[n][k] = W[k][n] * scale, cast to bf16.  Grid: (256, 2) x 256 thr.
__global__ void prep_wt(const float* __restrict__ Wk, unsigned short* __restrict__ WkT,
                        const float* __restrict__ Wq, unsigned short* __restrict__ WqT) {
  const float* W = blockIdx.y ? Wq : Wk;
  unsigned short* WT = blockIdx.y ? WqT : WkT;
  float scale = blockIdx.y ? 0.0625f : 1.0f;   // fold 1/sqrt(256) into Wq
  int idx = blockIdx.x * 256 + threadIdx.x;
  int n = idx >> 8, k = idx & 255;
  WT[n * 256 + k] = f2bf(W[k * 256 + n] * scale);
}

// Projection; output packed in 16x16x32-MFMA fragment order for 16-row tiles:
//   Yf[((t16*8 + kk)*64 + lane)*8 + j] = Y[row = t16*16 + (lane&15)]
//                                         [e  = kk*32 + (lane>>4)*8 + j]
__global__ __launch_bounds__(256, 2) void proj_kernel(
    const float* __restrict__ Xk, const unsigned short* __restrict__ WkT,
    unsigned short* __restrict__ Yk,
    const float* __restrict__ Xq, const unsigned short* __restrict__ WqT,
    unsigned short* __restrict__ Yq) {
  const float* X;
  const unsigned short* WT;
  unsigned short* Y;
  if (blockIdx.y == 0) { X = Xk; WT = WkT; Y = Yk; }
  else                 { X = Xq; WT = WqT; Y = Yq; }

  int tid = threadIdx.x;
  int wave = tid >> 6, lane = tid & 63;
  int l31 = lane & 31, kh = lane >> 5;
  int r0 = blockIdx.x * 128 + wave * 32;

  const float* xp = X + (size_t)(r0 + l31) * 256 + kh * 8;

  f32x16 acc[8];
#pragma unroll
  for (int ct = 0; ct < 8; ++ct)
#pragma unroll
    for (int i = 0; i < 16; ++i) acc[ct][i] = 0.0f;

#pragma unroll
  for (int kk = 0; kk < 16; ++kk) {
    f32x4 a0 = *(const f32x4*)(xp + kk * 16);
    f32x4 a1 = *(const f32x4*)(xp + kk * 16 + 4);
    s16x8 af;
#pragma unroll
    for (int j = 0; j < 4; ++j) {
      af[j]     = (short)f2bf(a0[j]);
      af[4 + j] = (short)f2bf(a1[j]);
    }
#pragma unroll
    for (int ct = 0; ct < 8; ++ct) {
      s16x8 bw = *(const s16x8*)(WT + (size_t)(ct * 32 + l31) * 256 + kk * 16 + kh * 8);
      acc[ct] = mfma32(af, bw, acc[ct]);
    }
  }

  // epilogue: scatter into 16-row-tile fragment order
  int kg2 = l31 >> 3, j = l31 & 7;
#pragma unroll
  for (int ct = 0; ct < 8; ++ct) {
#pragma unroll
    for (int r = 0; r < 16; ++r) {
      int rrow = (r & 3) + 8 * (r >> 2) + 4 * kh;
      int row = r0 + rrow;
      Y[((size_t)((row >> 4) * 8 + ct) * 64 + kg2 * 16 + (row & 15)) * 8 + j] =
          f2bf(acc[ct][r]);
    }
  }
}

// PERSISTENT-BLOCK fused attn: 256 blocks (1/CU), each owns 4 consecutive
// 32-row tiles of ONE batch (same K panel -> L2-resident all 4 tiles).
// Software pipeline across tiles: during tile t's epilogue stores, issue
// tile t+1's adjacency NT loads + pack + Q reload + K ct=0 prefetch.
// Eliminates the per-block phase serialization (adj prologue / store drain
// ran with compute idle at 1 block/CU) and 3 of 4 endpgm store-drains.
// Everything else = R17 (32 rows, A/B subtiles, K ping-pong, P in LDS).
// XCD remap: xcd = lin&7 owns batches {2*xcd, 2*xcd+1} (2 MB K / L2).
__global__ __launch_bounds__(512, 1) void attn_kernel(
    const unsigned short* __restrict__ Kf, const unsigned short* __restrict__ Qf,
    const int* __restrict__ adj, float* __restrict__ out) {
  int lin = blockIdx.y * 16 + blockIdx.x;   // grid (16,16) = 256 blocks
  int b  = (lin & 7) * 2 + ((lin >> 3) & 1);
  int tb = lin >> 4;                        // 0..15 -> row-tiles tb*4 .. tb*4+3
  int tid = threadIdx.x;
  int wave = tid >> 6, lane = tid & 63;
  int l15 = lane & 15, kg = lane >> 4;
  int colbase = wave * 256;

  __shared__ unsigned plds[8 * 16 * 256];  // 128 KB: [wave][ct][A:128|B:128]
  __shared__ unsigned lmask[8 * 288];      // 9 KB: 32 rows x 8 words, stride 9
  __shared__ float wsum[8][32];
  __shared__ float rrecip[32];

  const unsigned short* kfb = Kf + (size_t)b * 128 * 4096;   // same all tiles
  unsigned* pl = plds + wave * 4096 + lane * 2;
  unsigned* lm = lmask + wave * 288;

  int q0 = tb * 128;   // first tile's row base
  const i32x4* ap4 =
      (const i32x4*)(adj + ((size_t)b * NQ + q0) * (size_t)NK + colbase) + lane;
  const unsigned short* qp = Qf + (size_t)(b * 128 + tb * 8) * 4096;
  float* opBase = out + ((size_t)b * NQ + q0 + kg * 4) * (size_t)NK + colbase + l15;

  s16x8 aqA[8], aqB[8], bkX[8], bkY[8];

#define ADJ_LOAD(BASE, AV)                                                     \
  _Pragma("unroll") for (int r = 0; r < 16; ++r)                               \
      AV[r] = __builtin_nontemporal_load(ap4 + (size_t)((BASE) + r) * (NK / 4));

#define ADJ_PACK(BASE, AV)                                                     \
  _Pragma("unroll") for (int r = 0; r < 16; ++r) {                             \
    i32x4 v = AV[r];                                                           \
    unsigned nib = (v[0] != 0 ? 1u : 0u) | (v[1] != 0 ? 2u : 0u) |             \
                   (v[2] != 0 ? 4u : 0u) | (v[3] != 0 ? 8u : 0u);              \
    unsigned m = nib << ((lane & 7) * 4);                                      \
    m |= __shfl_xor(m, 1);                                                     \
    m |= __shfl_xor(m, 2);                                                     \
    m |= __shfl_xor(m, 4);                                                     \
    if ((lane & 7) == 0) lm[((BASE) + r) * 9 + (lane >> 3)] = m;               \
  }

#define QLOAD                                                                  \
  _Pragma("unroll") for (int kk = 0; kk < 8; ++kk) {                           \
    aqA[kk] = __builtin_nontemporal_load(                                      \
        (const s16x8*)(qp + ((size_t)kk * 64 + lane) * 8));                    \
    aqB[kk] = __builtin_nontemporal_load(                                      \
        (const s16x8*)(qp + 4096 + ((size_t)kk * 64 + lane) * 8));             \
  }

#define KLOAD(CT, DST)                                                         \
  {                                                                            \
    const unsigned short* kpt = kfb + (size_t)(wave * 16 + (CT)) * 4096;       \
    _Pragma("unroll") for (int kk = 0; kk < 8; ++kk)                           \
        DST[kk] = *(const s16x8*)(kpt + ((size_t)kk * 64 + lane) * 8);         \
  }

#define PROCESS(CT, BK)                                                        \
  {                                                                            \
    f32x4 accA = {0.0f, 0.0f, 0.0f, 0.0f};                                     \
    f32x4 accB = {0.0f, 0.0f, 0.0f, 0.0f};                                     \
    _Pragma("unroll") for (int kk = 0; kk < 8; ++kk) {                         \
      accA = mfma16(aqA[kk], BK[kk], accA);                                    \
      accB = mfma16(aqB[kk], BK[kk], accB);                                    \
    }                                                                          \
    unsigned shift = (unsigned)(((CT) & 1) * 16 + l15);                        \
    float pA[4], pB[4];                                                        \
    _Pragma("unroll") for (int r = 0; r < 4; ++r) {                            \
      unsigned mwA = lm[(kg * 4 + r) * 9 + ((CT) >> 1)];                       \
      unsigned mwB = lm[(16 + kg * 4 + r) * 9 + ((CT) >> 1)];                  \
      float eA = score_p(accA[r]);                                             \
      float eB = score_p(accB[r]);                                             \
      pA[r] = ((mwA >> shift) & 1u) ? eA : 0.0f;                               \
      pB[r] = ((mwB >> shift) & 1u) ? eB : 0.0f;                               \
      rsumA[r] += pA[r];                                                       \
      rsumB[r] += pB[r];                                                       \
    }                                                                          \
    u32x2 vA, vB;                                                              \
    vA[0] = (unsigned)f2bf(pA[0]) | ((unsigned)f2bf(pA[1]) << 16);             \
    vA[1] = (unsigned)f2bf(pA[2]) | ((unsigned)f2bf(pA[3]) << 16);             \
    vB[0] = (unsigned)f2bf(pB[0]) | ((unsigned)f2bf(pB[1]) << 16);             \
    vB[1] = (unsigned)f2bf(pB[2]) | ((unsigned)f2bf(pB[3]) << 16);             \
    *(u32x2*)(pl + (CT)*256) = vA;                                             \
    *(u32x2*)(pl + (CT)*256 + 128) = vB;                                       \
  }

#define STORE_CT(CT, OPA, OPB)                                                 \
  {                                                                            \
    u32x2 vA = *(const u32x2*)(pl + (CT)*256);                                 \
    u32x2 vB = *(const u32x2*)(pl + (CT)*256 + 128);                           \
    _Pragma("unroll") for (int r = 0; r < 4; ++r) {                            \
      unsigned w = (r < 2) ? vA[0] : vA[1];                                    \
      float p = __builtin_bit_cast(float, (r & 1) ? (w & 0xffff0000u) : (w << 16)); \
      __builtin_nontemporal_store(p * rcA[r], OPA + (size_t)r * NK + (CT)*16); \
    }                                                                          \
    _Pragma("unroll") for (int r = 0; r < 4; ++r) {                            \
      unsigned w = (r < 2) ? vB[0] : vB[1];                                    \
      float p = __builtin_bit_cast(float, (r & 1) ? (w & 0xffff0000u) : (w << 16)); \
      __builtin_nontemporal_store(p * rcB[r], OPB + (size_t)r * NK + (CT)*16); \
    }                                                                          \
  }

  // ---- prologue: tile 0's adjacency + Q + first K tile ----
  {
    i32x4 av[16];
    ADJ_LOAD(0, av)
    ADJ_PACK(0, av)
    ADJ_LOAD(16, av)
    ADJ_PACK(16, av)
  }
  QLOAD
  KLOAD(0, bkX)

#pragma unroll 1
  for (int t = 0; t < 4; ++t) {
    float rsumA[4] = {0.0f, 0.0f, 0.0f, 0.0f};
    float rsumB[4] = {0.0f, 0.0f, 0.0f, 0.0f};

    // ---- main loop: 16 col-tiles with K ping-pong ----
#pragma unroll
    for (int cp = 0; cp < 8; ++cp) {
      KLOAD(2 * cp + 1, bkY)
      PROCESS(2 * cp, bkX)
      if (cp < 7) KLOAD(2 * cp + 2, bkX)
      PROCESS(2 * cp + 1, bkY)
    }

    // ---- row-sum reduction ----
#pragma unroll
    for (int r = 0; r < 4; ++r) {
      float vA = rsumA[r], vB = rsumB[r];
      vA += __shfl_xor(vA, 1);  vB += __shfl_xor(vB, 1);
      vA += __shfl_xor(vA, 2);  vB += __shfl_xor(vB, 2);
      vA += __shfl_xor(vA, 4);  vB += __shfl_xor(vB, 4);
      vA += __shfl_xor(vA, 8);  vB += __shfl_xor(vB, 8);
      rsumA[r] = vA;  rsumB[r] = vB;
    }
    if (l15 == 0) {
#pragma unroll
      for (int r = 0; r < 4; ++r) {
        wsum[wave][kg * 4 + r]      = rsumA[r];
        wsum[wave][16 + kg * 4 + r] = rsumB[r];
      }
    }
    __syncthreads();
    if (tid < 32) {
      float s = 0.0f;
#pragma unroll
      for (int w = 0; w < 8; ++w) s += wsum[w][tid];
      rrecip[tid] = 1.0f / s;
    }
    __syncthreads();

    float rcA[4], rcB[4];
#pragma unroll
    for (int r = 0; r < 4; ++r) {
      rcA[r] = rrecip[kg * 4 + r];
      rcB[r] = rrecip[16 + kg * 4 + r];
    }

    float* opA = opBase;
    float* opB = opBase + (size_t)16 * NK;
    bool more = (t < 3);

    // advance pointers to next tile (safe: this tile's loads are all done)
    ap4 += (size_t)32 * (NK / 4);
    qp  += 8192;
    opBase += (size_t)32 * NK;

    // ---- epilogue interleaved with next tile's prologue ----
    i32x4 av[16];
    if (more) { ADJ_LOAD(0, av) }          // next tile rows 0..15 in flight
#pragma unroll
    for (int ct = 0; ct < 8; ++ct) { STORE_CT(ct, opA, opB) }
    if (more) {
      ADJ_PACK(0, av)                      // lmask free after main loop
      ADJ_LOAD(16, av)
    }
#pragma unroll
    for (int ct = 8; ct < 16; ++ct) { STORE_CT(ct, opA, opB) }
    if (more) {
      ADJ_PACK(16, av)
      QLOAD                                // aq free after main loop
      KLOAD(0, bkX)                        // prefetch next tile's first K tile
    }
  }
#undef ADJ_LOAD
#undef ADJ_PACK
#undef QLOAD
#undef KLOAD
#undef PROCESS
#undef STORE_CT
}

extern "C" void kernel_launch(void* const* d_in, const int* in_sizes, int n_in,
                              void* d_out, int out_size, void* d_ws, size_t ws_size,
                              hipStream_t stream) {
  const float* k_in = (const float*)d_in[0];
  const float* q_in = (const float*)d_in[1];
  const int* adj    = (const int*)d_in[2];
  const float* Wk   = (const float*)d_in[3];
  const float* Wq   = (const float*)d_in[4];
  float* out = (float*)d_out;

  char* ws = (char*)d_ws;
  unsigned short* WkT = (unsigned short*)(ws);                           // 128 KB
  unsigned short* WqT = (unsigned short*)(ws + (1u << 17));              // 128 KB
  unsigned short* Kf  = (unsigned short*)(ws + (1u << 18));              // 16 MB
  unsigned short* Qf  = (unsigned short*)(ws + (1u << 18) + (1u << 24)); // 16 MB

  prep_wt<<<dim3(256, 2), 256, 0, stream>>>(Wk, WkT, Wq, WqT);

  proj_kernel<<<dim3(256, 2), 256, 0, stream>>>(k_in, WkT, Kf, q_in, WqT, Qf);

  attn_kernel<<<dim3(16, 16), 512, 0, stream>>>(Kf, Qf, adj, out);
}

// Round 19
// 251.273 us; speedup vs baseline: 2.1904x; 2.1904x over previous
//
#include <hip/hip_runtime.h>

#define BATCH 16
#define NQ 2048
#define NK 2048

typedef short s16x8 __attribute__((ext_vector_type(8)));
typedef __bf16 bf16x8 __attribute__((ext_vector_type(8)));
typedef float f32x16 __attribute__((ext_vector_type(16)));
typedef float f32x4 __attribute__((ext_vector_type(4)));
typedef int i32x4 __attribute__((ext_vector_type(4)));
typedef unsigned u32x2 __attribute__((ext_vector_type(2)));

static __device__ __forceinline__ unsigned short f2bf(float f) {
  unsigned u = __builtin_bit_cast(unsigned, f);
  u += 0x7FFFu + ((u >> 16) & 1u);   // round-to-nearest-even
  return (unsigned short)(u >> 16);
}

static __device__ __forceinline__ f32x16 mfma32(s16x8 a, s16x8 b, f32x16 c) {
  return __builtin_amdgcn_mfma_f32_32x32x16_bf16(
      __builtin_bit_cast(bf16x8, a), __builtin_bit_cast(bf16x8, b), c, 0, 0, 0);
}

static __device__ __forceinline__ f32x4 mfma16(s16x8 a, s16x8 b, f32x4 c) {
  return __builtin_amdgcn_mfma_f32_16x16x32_bf16(
      __builtin_bit_cast(bf16x8, a), __builtin_bit_cast(bf16x8, b), c, 0, 0, 0);
}

// p = exp(10*tanh(s) - 10) = exp2(-28.8539.../(e^(2s)+1)), e^(2s)=exp2(2.88539*s)
static __device__ __forceinline__ float score_p(float s) {
  float u = __builtin_amdgcn_exp2f(s * 2.885390081777927f);
  return __builtin_amdgcn_exp2f(-28.853900817779268f * __builtin_amdgcn_rcpf(u + 1.0f));
}

// WT[n][k] = W[k][n] * scale, cast to bf16.  Grid: (256, 2) x 256 thr.
__global__ void prep_wt(const float* __restrict__ Wk, unsigned short* __restrict__ WkT,
                        const float* __restrict__ Wq, unsigned short* __restrict__ WqT) {
  const float* W = blockIdx.y ? Wq : Wk;
  unsigned short* WT = blockIdx.y ? WqT : WkT;
  float scale = blockIdx.y ? 0.0625f : 1.0f;   // fold 1/sqrt(256) into Wq
  int idx = blockIdx.x * 256 + threadIdx.x;
  int n = idx >> 8, k = idx & 255;
  WT[n * 256 + k] = f2bf(W[k * 256 + n] * scale);
}

// Pack adjacency int32 (0/1) into bitmask words (proven R2 kernel, ~50 us
// pure streaming at >5 TB/s). Each wave handles 2048 consecutive ints
// (= one (b,q) row) -> 64 uint32 words. Word w covers cols w*32..w*32+31,
// bit = col&31. Grid: 8192 blocks x 256 threads.
__global__ __launch_bounds__(256) void pack_adj(const int* __restrict__ adj,
                                                unsigned* __restrict__ mask) {
  int gwave = (blockIdx.x * 256 + threadIdx.x) >> 6;
  int lane = threadIdx.x & 63;
  const int* p = adj + (size_t)gwave * 2048;
  unsigned my = 0;
#pragma unroll
  for (int c = 0; c < 32; ++c) {
    int a = p[c * 64 + lane];
    unsigned long long m = __ballot(a != 0);
    if ((lane >> 1) == c) my = (lane & 1) ? (unsigned)(m >> 32) : (unsigned)m;
  }
  mask[(size_t)gwave * 64 + lane] = my;
}

// Projection; output packed in 16x16x32-MFMA fragment order for 16-row tiles:
//   Yf[((t16*8 + kk)*64 + lane)*8 + j] = Y[row = t16*16 + (lane&15)]
//                                         [e  = kk*32 + (lane>>4)*8 + j]
__global__ __launch_bounds__(256, 2) void proj_kernel(
    const float* __restrict__ Xk, const unsigned short* __restrict__ WkT,
    unsigned short* __restrict__ Yk,
    const float* __restrict__ Xq, const unsigned short* __restrict__ WqT,
    unsigned short* __restrict__ Yq) {
  const float* X;
  const unsigned short* WT;
  unsigned short* Y;
  if (blockIdx.y == 0) { X = Xk; WT = WkT; Y = Yk; }
  else                 { X = Xq; WT = WqT; Y = Yq; }

  int tid = threadIdx.x;
  int wave = tid >> 6, lane = tid & 63;
  int l31 = lane & 31, kh = lane >> 5;
  int r0 = blockIdx.x * 128 + wave * 32;

  const float* xp = X + (size_t)(r0 + l31) * 256 + kh * 8;

  f32x16 acc[8];
#pragma unroll
  for (int ct = 0; ct < 8; ++ct)
#pragma unroll
    for (int i = 0; i < 16; ++i) acc[ct][i] = 0.0f;

#pragma unroll
  for (int kk = 0; kk < 16; ++kk) {
    f32x4 a0 = *(const f32x4*)(xp + kk * 16);
    f32x4 a1 = *(const f32x4*)(xp + kk * 16 + 4);
    s16x8 af;
#pragma unroll
    for (int j = 0; j < 4; ++j) {
      af[j]     = (short)f2bf(a0[j]);
      af[4 + j] = (short)f2bf(a1[j]);
    }
#pragma unroll
    for (int ct = 0; ct < 8; ++ct) {
      s16x8 bw = *(const s16x8*)(WT + (size_t)(ct * 32 + l31) * 256 + kk * 16 + kh * 8);
      acc[ct] = mfma32(af, bw, acc[ct]);
    }
  }

  // epilogue: scatter into 16-row-tile fragment order
  int kg2 = l31 >> 3, j = l31 & 7;
#pragma unroll
  for (int ct = 0; ct < 8; ++ct) {
#pragma unroll
    for (int r = 0; r < 16; ++r) {
      int rrow = (r & 3) + 8 * (r >> 2) + 4 * kh;
      int row = r0 + rrow;
      Y[((size_t)((row >> 4) * 8 + ct) * 64 + kg2 * 16 + (row & 15)) * 8 + j] =
          f2bf(acc[ct][r]);
    }
  }
}

// Fused scores + tanh-clip + mask + softmax, ONE-PASS, 32 Q-rows per block
// (two 16-row subtiles A/B share every K fragment -> K L2 traffic halved;
// R17 structure = best known). Changes vs R17:
//  - adjacency pack moved OUT (pack_adj streams it at ~5 TB/s); attn stages
//    its 8 KB of mask words into LDS (1 x i32x4/thread + one barrier).
//    Removes 256 MB of HBM reads from this kernel's critical path.
//  - output stores PLAIN (not NT): R10/R11 evidence shows NT 64B-quarter
//    stores inflate WRITE ~25% (partial-line RMW); L2 write-combining wins.
// Grid: (64, 16) = 1024 blocks, 512 threads (8 waves); wave w owns cols
// [w*256, w*256+256) as 16 col-tiles of 16. K ping-pong prefetch.
// P stash in LDS 128 KB + masks ~8.7 KB -> 1 block/CU by LDS.
// XCD remap: xcd = lin&7 owns batches {2*xcd, 2*xcd+1} (2 MB K / L2).
__global__ __launch_bounds__(512, 1) void attn_kernel(
    const unsigned short* __restrict__ Kf, const unsigned short* __restrict__ Qf,
    const unsigned* __restrict__ mask, float* __restrict__ out) {
  int lin = blockIdx.y * 64 + blockIdx.x;
  int b  = (lin & 7) * 2 + ((lin >> 3) & 1);
  int qt = lin >> 4;                 // 0..63: 32-row tile within batch
  int q0 = qt * 32;
  int tid = threadIdx.x;
  int wave = tid >> 6, lane = tid & 63;
  int l15 = lane & 15, kg = lane >> 4;
  int colbase = wave * 256;

  __shared__ unsigned plds[8 * 16 * 256];  // 128 KB: [wave][ct][A:128|B:128]
  __shared__ unsigned lmask[32 * 68];      // 8.7 KB: [row][word], stride 68
  __shared__ float wsum[8][32];
  __shared__ float rrecip[32];

  // ---- stage mask words: rows q0..q0+31, 64 words each (2048 words) ----
  {
    const i32x4* msrc = (const i32x4*)(mask + ((size_t)b * NQ + q0) * 64);
    i32x4 v = msrc[tid];
    int row = tid >> 4, w4 = tid & 15;          // word group w4*4..w4*4+3
    *(i32x4*)(lmask + row * 68 + w4 * 4) = v;   // 68%4==0: aligned
  }

  // Q fragments for subtiles A (rows q0..q0+15) and B (rows q0+16..q0+31)
  const unsigned short* qpA = Qf + (size_t)(b * 128 + 2 * qt) * 4096;
  s16x8 aqA[8], aqB[8];
#pragma unroll
  for (int kk = 0; kk < 8; ++kk) {
    aqA[kk] = __builtin_nontemporal_load(
        (const s16x8*)(qpA + ((size_t)kk * 64 + lane) * 8));
    aqB[kk] = __builtin_nontemporal_load(
        (const s16x8*)(qpA + 4096 + ((size_t)kk * 64 + lane) * 8));
  }

  __syncthreads();  // lmask staged cross-wave

  const unsigned short* kfb = Kf + (size_t)b * 128 * 4096;
  unsigned* pl = plds + wave * 4096 + lane * 2;

  float rsumA[4] = {0.0f, 0.0f, 0.0f, 0.0f};
  float rsumB[4] = {0.0f, 0.0f, 0.0f, 0.0f};
  s16x8 bkX[8], bkY[8];

#define KLOAD(CT, DST)                                                         \
  {                                                                            \
    const unsigned short* kpt = kfb + (size_t)(wave * 16 + (CT)) * 4096;       \
    _Pragma("unroll") for (int kk = 0; kk < 8; ++kk)                           \
        DST[kk] = *(const s16x8*)(kpt + ((size_t)kk * 64 + lane) * 8);         \
  }

#define PROCESS(CT, BK)                                                        \
  {                                                                            \
    f32x4 accA = {0.0f, 0.0f, 0.0f, 0.0f};                                     \
    f32x4 accB = {0.0f, 0.0f, 0.0f, 0.0f};                                     \
    _Pragma("unroll") for (int kk = 0; kk < 8; ++kk) {                         \
      accA = mfma16(aqA[kk], BK[kk], accA);                                    \
      accB = mfma16(aqB[kk], BK[kk], accB);                                    \
    }                                                                          \
    unsigned shift = (unsigned)(((CT) & 1) * 16 + l15);                        \
    int wrd = wave * 8 + ((CT) >> 1);                                          \
    float pA[4], pB[4];                                                        \
    _Pragma("unroll") for (int r = 0; r < 4; ++r) {                            \
      unsigned mwA = lmask[(kg * 4 + r) * 68 + wrd];                           \
      unsigned mwB = lmask[(16 + kg * 4 + r) * 68 + wrd];                      \
      float eA = score_p(accA[r]);                                             \
      float eB = score_p(accB[r]);                                             \
      pA[r] = ((mwA >> shift) & 1u) ? eA : 0.0f;                               \
      pB[r] = ((mwB >> shift) & 1u) ? eB : 0.0f;                               \
      rsumA[r] += pA[r];                                                       \
      rsumB[r] += pB[r];                                                       \
    }                                                                          \
    u32x2 vA, vB;                                                              \
    vA[0] = (unsigned)f2bf(pA[0]) | ((unsigned)f2bf(pA[1]) << 16);             \
    vA[1] = (unsigned)f2bf(pA[2]) | ((unsigned)f2bf(pA[3]) << 16);             \
    vB[0] = (unsigned)f2bf(pB[0]) | ((unsigned)f2bf(pB[1]) << 16);             \
    vB[1] = (unsigned)f2bf(pB[2]) | ((unsigned)f2bf(pB[3]) << 16);             \
    *(u32x2*)(pl + (CT)*256) = vA;                                             \
    *(u32x2*)(pl + (CT)*256 + 128) = vB;                                       \
  }

  KLOAD(0, bkX)
#pragma unroll
  for (int cp = 0; cp < 8; ++cp) {
    KLOAD(2 * cp + 1, bkY)      // prefetch odd tile before consuming even
    PROCESS(2 * cp, bkX)
    if (cp < 7) KLOAD(2 * cp + 2, bkX)   // prefetch next even before odd
    PROCESS(2 * cp + 1, bkY)
  }
#undef KLOAD
#undef PROCESS

  // col-reduce within each 16-lane quarter (rows disjoint across quarters)
#pragma unroll
  for (int r = 0; r < 4; ++r) {
    float vA = rsumA[r], vB = rsumB[r];
    vA += __shfl_xor(vA, 1);  vB += __shfl_xor(vB, 1);
    vA += __shfl_xor(vA, 2);  vB += __shfl_xor(vB, 2);
    vA += __shfl_xor(vA, 4);  vB += __shfl_xor(vB, 4);
    vA += __shfl_xor(vA, 8);  vB += __shfl_xor(vB, 8);
    rsumA[r] = vA;  rsumB[r] = vB;
  }
  if (l15 == 0) {
#pragma unroll
    for (int r = 0; r < 4; ++r) {
      wsum[wave][kg * 4 + r]      = rsumA[r];
      wsum[wave][16 + kg * 4 + r] = rsumB[r];
    }
  }
  __syncthreads();
  if (tid < 32) {
    float s = 0.0f;
#pragma unroll
    for (int w = 0; w < 8; ++w) s += wsum[w][tid];
    rrecip[tid] = 1.0f / s;
  }
  __syncthreads();

  float rcA[4], rcB[4];
#pragma unroll
  for (int r = 0; r < 4; ++r) {
    rcA[r] = rrecip[kg * 4 + r];
    rcB[r] = rrecip[16 + kg * 4 + r];
  }

  // read P back from LDS, normalize, PLAIN stores (L2 write-combining)
  float* opA = out + ((size_t)b * NQ + q0 + kg * 4) * (size_t)NK + colbase + l15;
  float* opB = opA + (size_t)16 * NK;
#pragma unroll 4
  for (int ct = 0; ct < 16; ++ct) {
    u32x2 vA = *(const u32x2*)(pl + ct * 256);
    u32x2 vB = *(const u32x2*)(pl + ct * 256 + 128);
#pragma unroll
    for (int r = 0; r < 4; ++r) {
      unsigned w = (r < 2) ? vA[0] : vA[1];
      float p = __builtin_bit_cast(float, (r & 1) ? (w & 0xffff0000u) : (w << 16));
      opA[(size_t)r * NK + ct * 16] = p * rcA[r];
    }
#pragma unroll
    for (int r = 0; r < 4; ++r) {
      unsigned w = (r < 2) ? vB[0] : vB[1];
      float p = __builtin_bit_cast(float, (r & 1) ? (w & 0xffff0000u) : (w << 16));
      opB[(size_t)r * NK + ct * 16] = p * rcB[r];
    }
  }
}

extern "C" void kernel_launch(void* const* d_in, const int* in_sizes, int n_in,
                              void* d_out, int out_size, void* d_ws, size_t ws_size,
                              hipStream_t stream) {
  const float* k_in = (const float*)d_in[0];
  const float* q_in = (const float*)d_in[1];
  const int* adj    = (const int*)d_in[2];
  const float* Wk   = (const float*)d_in[3];
  const float* Wq   = (const float*)d_in[4];
  float* out = (float*)d_out;

  char* ws = (char*)d_ws;
  unsigned short* WkT = (unsigned short*)(ws);                           // 128 KB
  unsigned short* WqT = (unsigned short*)(ws + (1u << 17));              // 128 KB
  unsigned short* Kf  = (unsigned short*)(ws + (1u << 18));              // 16 MB
  unsigned short* Qf  = (unsigned short*)(ws + (1u << 18) + (1u << 24)); // 16 MB
  unsigned* maskbuf   = (unsigned*)(ws + (1u << 18) + (2u << 24));       // 8.4 MB

  prep_wt<<<dim3(256, 2), 256, 0, stream>>>(Wk, WkT, Wq, WqT);

  pack_adj<<<(BATCH * NQ * NK) / (2048 * 4), 256, 0, stream>>>(adj, maskbuf);

  proj_kernel<<<dim3(256, 2), 256, 0, stream>>>(k_in, WkT, Kf, q_in, WqT, Qf);

  attn_kernel<<<dim3(64, 16), 512, 0, stream>>>(Kf, Qf, maskbuf, out);
}

// Round 20
// 220.560 us; speedup vs baseline: 2.4955x; 1.1392x over previous
//
#include <hip/hip_runtime.h>

#define BATCH 16
#define NQ 2048
#define NK 2048

typedef short s16x8 __attribute__((ext_vector_type(8)));
typedef __bf16 bf16x8 __attribute__((ext_vector_type(8)));
typedef float f32x16 __attribute__((ext_vector_type(16)));
typedef float f32x4 __attribute__((ext_vector_type(4)));
typedef int i32x4 __attribute__((ext_vector_type(4)));
typedef unsigned u32x2 __attribute__((ext_vector_type(2)));

static __device__ __forceinline__ unsigned short f2bf(float f) {
  unsigned u = __builtin_bit_cast(unsigned, f);
  u += 0x7FFFu + ((u >> 16) & 1u);   // round-to-nearest-even
  return (unsigned short)(u >> 16);
}

static __device__ __forceinline__ f32x16 mfma32(s16x8 a, s16x8 b, f32x16 c) {
  return __builtin_amdgcn_mfma_f32_32x32x16_bf16(
      __builtin_bit_cast(bf16x8, a), __builtin_bit_cast(bf16x8, b), c, 0, 0, 0);
}

static __device__ __forceinline__ f32x4 mfma16(s16x8 a, s16x8 b, f32x4 c) {
  return __builtin_amdgcn_mfma_f32_16x16x32_bf16(
      __builtin_bit_cast(bf16x8, a), __builtin_bit_cast(bf16x8, b), c, 0, 0, 0);
}

// p = exp(10*tanh(s) - 10) = exp2(-28.8539.../(e^(2s)+1)), e^(2s)=exp2(2.88539*s)
static __device__ __forceinline__ float score_p(float s) {
  float u = __builtin_amdgcn_exp2f(s * 2.885390081777927f);
  return __builtin_amdgcn_exp2f(-28.853900817779268f * __builtin_amdgcn_rcpf(u + 1.0f));
}

// MERGED prep kernel: pack_adj + both projections in ONE launch so the
// 256 MB adjacency stream overlaps the projection MFMA work (they were
// serial kernels costing 50+28 us; combined HBM floor ~60 us).
//  - blocks 0..255:   K projection (blocks stage their own W^T in LDS)
//  - blocks 256..511: Q projection (scale 1/16 folded)
//  - blocks 512..8703: adjacency bit-pack (R2-proven layout)
// One static LDS block (32 KB) for all: W^T staged in FOUR 64-k stages so
// 2 proj (64 KB) + 3 pack blocks co-reside per CU. W is 512 KB -> L3-hot,
// so per-block re-transposition costs L3 BW only, and removes the
// prep_wt->proj dependency that forced serialization.
// LDS fragment layout XOR-swizzled: elem (n, kl) at
//   wtl[n*64 + ((kl>>3) ^ (n&7))*8 + (kl&7)]
// -> b128 fragment reads land 8 words/bank uniform (the b128 minimum),
//    16 B aligned (row stride 128 B).
__global__ __launch_bounds__(256, 2) void prep_all(
    const float* __restrict__ Xk, const float* __restrict__ Xq,
    const float* __restrict__ Wk, const float* __restrict__ Wq,
    const int* __restrict__ adj,
    unsigned short* __restrict__ Yk, unsigned short* __restrict__ Yq,
    unsigned* __restrict__ mask) {
  __shared__ unsigned short wtl[256 * 64];   // 32 KB
  int bid = blockIdx.x;
  int tid = threadIdx.x;

  if (bid >= 512) {
    // ---- adjacency pack: wave handles one (b,q) row of 2048 ints ----
    int gwave = ((bid - 512) * 256 + tid) >> 6;
    int lane = tid & 63;
    const int* p = adj + (size_t)gwave * 2048;
    unsigned my = 0;
#pragma unroll
    for (int c = 0; c < 32; ++c) {
      int a = p[c * 64 + lane];
      unsigned long long m = __ballot(a != 0);
      if ((lane >> 1) == c) my = (lane & 1) ? (unsigned)(m >> 32) : (unsigned)m;
    }
    mask[(size_t)gwave * 64 + lane] = my;
    return;
  }

  // ---- projection ----
  const float* X;
  const float* W;
  unsigned short* Y;
  float scale;
  if (bid < 256) { X = Xk; W = Wk; Y = Yk; scale = 1.0f; }
  else           { X = Xq; W = Wq; Y = Yq; scale = 0.0625f; }
  int xb = bid & 255;
  int wave = tid >> 6, lane = tid & 63;
  int l31 = lane & 31, kh = lane >> 5;
  int r0 = xb * 128 + wave * 32;

  const float* xp = X + (size_t)(r0 + l31) * 256 + kh * 8;

  f32x16 acc[8];
#pragma unroll
  for (int ct = 0; ct < 8; ++ct)
#pragma unroll
    for (int i = 0; i < 16; ++i) acc[ct][i] = 0.0f;

#pragma unroll 1
  for (int s = 0; s < 4; ++s) {
    __syncthreads();   // previous stage fully consumed
    // stage W rows k = s*64 .. s*64+63 as bf16 W^T into LDS (swizzled)
#pragma unroll 16
    for (int kl = 0; kl < 64; ++kl) {
      int k = s * 64 + kl;
      float w = W[(size_t)k * 256 + tid] * scale;   // coalesced 1 KB/iter
      wtl[tid * 64 + (((kl >> 3) ^ (tid & 7)) << 3) + (kl & 7)] = f2bf(w);
    }
    __syncthreads();   // stage visible to all waves

#pragma unroll
    for (int kq = 0; kq < 4; ++kq) {
      int kk = s * 4 + kq;   // global 16-k index, 0..15 over the 4 stages
      f32x4 a0 = *(const f32x4*)(xp + kk * 16);
      f32x4 a1 = *(const f32x4*)(xp + kk * 16 + 4);
      s16x8 af;
#pragma unroll
      for (int j = 0; j < 4; ++j) {
        af[j]     = (short)f2bf(a0[j]);
        af[4 + j] = (short)f2bf(a1[j]);
      }
      int bk = kq * 2 + kh;   // 16B-block index within stage, 0..7
#pragma unroll
      for (int ct = 0; ct < 8; ++ct) {
        int n = ct * 32 + l31;
        s16x8 bw = *(const s16x8*)(wtl + n * 64 + ((bk ^ (n & 7)) << 3));
        acc[ct] = mfma32(af, bw, acc[ct]);
      }
    }
  }

  // epilogue: scatter into 16-row-tile fragment order (unchanged layout):
  //   Yf[((t16*8 + kk)*64 + lane)*8 + j] = Y[row=t16*16+(lane&15)][e=kk*32+(lane>>4)*8+j]
  int kg2 = l31 >> 3, j = l31 & 7;
#pragma unroll
  for (int ct = 0; ct < 8; ++ct) {
#pragma unroll
    for (int r = 0; r < 16; ++r) {
      int rrow = (r & 3) + 8 * (r >> 2) + 4 * kh;
      int row = r0 + rrow;
      Y[((size_t)((row >> 4) * 8 + ct) * 64 + kg2 * 16 + (row & 15)) * 8 + j] =
          f2bf(acc[ct][r]);
    }
  }
}

// Fused scores + tanh-clip + mask + softmax, ONE-PASS, 32 Q-rows per block
// (two 16-row subtiles A/B share every K fragment -> K L2 traffic halved).
// Masks from the packed bitmask (staged 8 KB -> LDS); plain output stores.
// Grid: (64, 16) = 1024 blocks, 512 threads (8 waves); wave w owns cols
// [w*256, w*256+256) as 16 col-tiles of 16. K ping-pong prefetch.
// P stash in LDS 128 KB + masks ~8.7 KB -> 1 block/CU by LDS.
// XCD remap: xcd = lin&7 owns batches {2*xcd, 2*xcd+1} (2 MB K / L2).
__global__ __launch_bounds__(512, 1) void attn_kernel(
    const unsigned short* __restrict__ Kf, const unsigned short* __restrict__ Qf,
    const unsigned* __restrict__ mask, float* __restrict__ out) {
  int lin = blockIdx.y * 64 + blockIdx.x;
  int b  = (lin & 7) * 2 + ((lin >> 3) & 1);
  int qt = lin >> 4;                 // 0..63: 32-row tile within batch
  int q0 = qt * 32;
  int tid = threadIdx.x;
  int wave = tid >> 6, lane = tid & 63;
  int l15 = lane & 15, kg = lane >> 4;
  int colbase = wave * 256;

  __shared__ unsigned plds[8 * 16 * 256];  // 128 KB: [wave][ct][A:128|B:128]
  __shared__ unsigned lmask[32 * 68];      // 8.7 KB: [row][word], stride 68
  __shared__ float wsum[8][32];
  __shared__ float rrecip[32];

  // ---- stage mask words: rows q0..q0+31, 64 words each (2048 words) ----
  {
    const i32x4* msrc = (const i32x4*)(mask + ((size_t)b * NQ + q0) * 64);
    i32x4 v = msrc[tid];
    int row = tid >> 4, w4 = tid & 15;          // word group w4*4..w4*4+3
    *(i32x4*)(lmask + row * 68 + w4 * 4) = v;   // 68%4==0: aligned
  }

  // Q fragments for subtiles A (rows q0..q0+15) and B (rows q0+16..q0+31)
  const unsigned short* qpA = Qf + (size_t)(b * 128 + 2 * qt) * 4096;
  s16x8 aqA[8], aqB[8];
#pragma unroll
  for (int kk = 0; kk < 8; ++kk) {
    aqA[kk] = __builtin_nontemporal_load(
        (const s16x8*)(qpA + ((size_t)kk * 64 + lane) * 8));
    aqB[kk] = __builtin_nontemporal_load(
        (const s16x8*)(qpA + 4096 + ((size_t)kk * 64 + lane) * 8));
  }

  __syncthreads();  // lmask staged cross-wave

  const unsigned short* kfb = Kf + (size_t)b * 128 * 4096;
  unsigned* pl = plds + wave * 4096 + lane * 2;

  float rsumA[4] = {0.0f, 0.0f, 0.0f, 0.0f};
  float rsumB[4] = {0.0f, 0.0f, 0.0f, 0.0f};
  s16x8 bkX[8], bkY[8];

#define KLOAD(CT, DST)                                                         \
  {                                                                            \
    const unsigned short* kpt = kfb + (size_t)(wave * 16 + (CT)) * 4096;       \
    _Pragma("unroll") for (int kk = 0; kk < 8; ++kk)                           \
        DST[kk] = *(const s16x8*)(kpt + ((size_t)kk * 64 + lane) * 8);         \
  }

#define PROCESS(CT, BK)                                                        \
  {                                                                            \
    f32x4 accA = {0.0f, 0.0f, 0.0f, 0.0f};                                     \
    f32x4 accB = {0.0f, 0.0f, 0.0f, 0.0f};                                     \
    _Pragma("unroll") for (int kk = 0; kk < 8; ++kk) {                         \
      accA = mfma16(aqA[kk], BK[kk], accA);                                    \
      accB = mfma16(aqB[kk], BK[kk], accB);                                    \
    }                                                                          \
    unsigned shift = (unsigned)(((CT) & 1) * 16 + l15);                        \
    int wrd = wave * 8 + ((CT) >> 1);                                          \
    float pA[4], pB[4];                                                        \
    _Pragma("unroll") for (int r = 0; r < 4; ++r) {                            \
      unsigned mwA = lmask[(kg * 4 + r) * 68 + wrd];                           \
      unsigned mwB = lmask[(16 + kg * 4 + r) * 68 + wrd];                      \
      float eA = score_p(accA[r]);                                             \
      float eB = score_p(accB[r]);                                             \
      pA[r] = ((mwA >> shift) & 1u) ? eA : 0.0f;                               \
      pB[r] = ((mwB >> shift) & 1u) ? eB : 0.0f;                               \
      rsumA[r] += pA[r];                                                       \
      rsumB[r] += pB[r];                                                       \
    }                                                                          \
    u32x2 vA, vB;                                                              \
    vA[0] = (unsigned)f2bf(pA[0]) | ((unsigned)f2bf(pA[1]) << 16);             \
    vA[1] = (unsigned)f2bf(pA[2]) | ((unsigned)f2bf(pA[3]) << 16);             \
    vB[0] = (unsigned)f2bf(pB[0]) | ((unsigned)f2bf(pB[1]) << 16);             \
    vB[1] = (unsigned)f2bf(pB[2]) | ((unsigned)f2bf(pB[3]) << 16);             \
    *(u32x2*)(pl + (CT)*256) = vA;                                             \
    *(u32x2*)(pl + (CT)*256 + 128) = vB;                                       \
  }

  KLOAD(0, bkX)
#pragma unroll
  for (int cp = 0; cp < 8; ++cp) {
    KLOAD(2 * cp + 1, bkY)      // prefetch odd tile before consuming even
    PROCESS(2 * cp, bkX)
    if (cp < 7) KLOAD(2 * cp + 2, bkX)   // prefetch next even before odd
    PROCESS(2 * cp + 1, bkY)
  }
#undef KLOAD
#undef PROCESS

  // col-reduce within each 16-lane quarter (rows disjoint across quarters)
#pragma unroll
  for (int r = 0; r < 4; ++r) {
    float vA = rsumA[r], vB = rsumB[r];
    vA += __shfl_xor(vA, 1);  vB += __shfl_xor(vB, 1);
    vA += __shfl_xor(vA, 2);  vB += __shfl_xor(vB, 2);
    vA += __shfl_xor(vA, 4);  vB += __shfl_xor(vB, 4);
    vA += __shfl_xor(vA, 8);  vB += __shfl_xor(vB, 8);
    rsumA[r] = vA;  rsumB[r] = vB;
  }
  if (l15 == 0) {
#pragma unroll
    for (int r = 0; r < 4; ++r) {
      wsum[wave][kg * 4 + r]      = rsumA[r];
      wsum[wave][16 + kg * 4 + r] = rsumB[r];
    }
  }
  __syncthreads();
  if (tid < 32) {
    float s = 0.0f;
#pragma unroll
    for (int w = 0; w < 8; ++w) s += wsum[w][tid];
    rrecip[tid] = 1.0f / s;
  }
  __syncthreads();

  float rcA[4], rcB[4];
#pragma unroll
  for (int r = 0; r < 4; ++r) {
    rcA[r] = rrecip[kg * 4 + r];
    rcB[r] = rrecip[16 + kg * 4 + r];
  }

  // read P back from LDS, normalize, PLAIN stores (L2 write-combining)
  float* opA = out + ((size_t)b * NQ + q0 + kg * 4) * (size_t)NK + colbase + l15;
  float* opB = opA + (size_t)16 * NK;
#pragma unroll 4
  for (int ct = 0; ct < 16; ++ct) {
    u32x2 vA = *(const u32x2*)(pl + ct * 256);
    u32x2 vB = *(const u32x2*)(pl + ct * 256 + 128);
#pragma unroll
    for (int r = 0; r < 4; ++r) {
      unsigned w = (r < 2) ? vA[0] : vA[1];
      float p = __builtin_bit_cast(float, (r & 1) ? (w & 0xffff0000u) : (w << 16));
      opA[(size_t)r * NK + ct * 16] = p * rcA[r];
    }
#pragma unroll
    for (int r = 0; r < 4; ++r) {
      unsigned w = (r < 2) ? vB[0] : vB[1];
      float p = __builtin_bit_cast(float, (r & 1) ? (w & 0xffff0000u) : (w << 16));
      opB[(size_t)r * NK + ct * 16] = p * rcB[r];
    }
  }
}

extern "C" void kernel_launch(void* const* d_in, const int* in_sizes, int n_in,
                              void* d_out, int out_size, void* d_ws, size_t ws_size,
                              hipStream_t stream) {
  const float* k_in = (const float*)d_in[0];
  const float* q_in = (const float*)d_in[1];
  const int* adj    = (const int*)d_in[2];
  const float* Wk   = (const float*)d_in[3];
  const float* Wq   = (const float*)d_in[4];
  float* out = (float*)d_out;

  char* ws = (char*)d_ws;
  unsigned short* Kf  = (unsigned short*)(ws + (1u << 18));              // 16 MB
  unsigned short* Qf  = (unsigned short*)(ws + (1u << 18) + (1u << 24)); // 16 MB
  unsigned* maskbuf   = (unsigned*)(ws + (1u << 18) + (2u << 24));       // 8.4 MB

  prep_all<<<512 + 8192, 256, 0, stream>>>(k_in, q_in, Wk, Wq, adj,
                                           Kf, Qf, maskbuf);

  attn_kernel<<<dim3(64, 16), 512, 0, stream>>>(Kf, Qf, maskbuf, out);
}